// Round 10
// baseline (1313.264 us; speedup 1.0000x reference)
//
// R13: de-lockstepped FAST path — 1 barrier/step (was 3), per-wave subflags.
// R12 post-mortem: operand-swap matched (1216->1188, conflicts -7%); step
// ~5400cy vs ~2500cy phase sum -> residual is lockstep: 3 syncthreads/step +
// (slowest-wave + barrier + tid0 signal) on the producer side + (wave0 poll +
// barrier) on the consumer side. R13 (FAST only; slow path keeps 3 barriers):
//  - flags: 64 per-(layer,gb) per-WAVE subflags (16B stride, same 16KB
//    region). Producer wave: s_waitcnt vmcnt(0) (subset of run-proven inv_l1
//    asm) then lane0 stores subflag -> no end barrier, earliest handoff.
//  - consumers: ALL waves poll (lane l: own-layer subflag l + other-layer
//    subflag l; thresholds byte-identical to R12) -> no post-poll barrier.
//  - inA double-buffered [2][MB][LDSK] (buf = t&1) -> staging for t+1 cannot
//    race mfma reads of t; the one surviving barrier is staging->MFMA.
//  - x[t+1] prefetch issued inside staging so per-wave vmcnt(0) never waits
//    on fresh HBM loads. gbuf deleted (discovery scratch -> inA pre-zero).
// Proven kept: XCD fast path + verdict, sc1 polls, plain-store comm + inv_l1,
// scalar staging, operand-swapped MFMA + in-register gates, distributed head.
#include <hip/hip_runtime.h>
#include <cstdint>

#define B_TOT 256
#define T_LEN 512
#define NX    40
#define NH    250
#define HP    256          // hidden padded (dummy units produce h=0, W cols 0)
#define XP    64           // x padded
#define K0    (XP + HP)    // 320  (layer0: [x | h1_prev])
#define K1    (HP + HP)    // 512  (layer1: [h1_t | h2_prev])
#define MB    32           // batches per wg
#define NU    16           // hidden units per wg
#define NR    64           // gate rows per wg (NU*4, r = lu*4 + gate; i,f,g,o)
#define RING  8            // broadcast ring depth
#define LDSK  520          // LDS K-stride in ushorts (16B aligned; 260 dwords)
#define NFLAG 4096         // 16 groups x 64 subflags x 4 ints = 16KB (as before)
#define GSTRIDE 256        // ints per (layer,gb) group: 64 subflags x 4 ints
#define RSTEP (B_TOT * HP / 2)       // 32768 dwords per ring slot
// h ring (dwords): slot*RSTEP + gb*4096 + gg*256 + eb*8 + up
//   where dword (gg,up) of batch eb = bf16 units (gg*16+2up, gg*16+2up+1)
// discovery state in subflag padding ints (int0 of each 4-int slot is the
// only flag pollers touch): xcd id of wg w at cnt[w*4+1], barrier at cnt[3].
#define XCD_AT(w) ((w) * 4 + 1)
#define BAR_IDX 3
// s_getreg imm: id | (offset<<6) | ((size-1)<<11); XCC_ID id=20, 32 bits.
#define GETREG_XCC 63508

typedef __attribute__((ext_vector_type(8))) short short8;
typedef __attribute__((ext_vector_type(4))) float float4v;

__device__ __forceinline__ unsigned short f2bf(float f) {
  unsigned u = __float_as_uint(f);
  u += 0x7FFFu + ((u >> 16) & 1u);          // RNE
  return (unsigned short)(u >> 16);
}
__device__ __forceinline__ float bf2f(unsigned short h) {
  return __uint_as_float(((unsigned)h) << 16);
}
__device__ __forceinline__ float sigm(float x) { return 1.0f / (1.0f + __expf(-x)); }
__device__ __forceinline__ float tanh_f(float x) {
  float e = __expf(-2.0f * fabsf(x));
  float t = (1.0f - e) / (1.0f + e);
  return copysignf(t, x);
}
__device__ __forceinline__ int ld_flag(const int* p) {            // sc1 dword load
  return __hip_atomic_load(p, __ATOMIC_RELAXED, __HIP_MEMORY_SCOPE_AGENT);
}
__device__ __forceinline__ unsigned ld_lic(const unsigned* p) {
  return __hip_atomic_load(p, __ATOMIC_RELAXED, __HIP_MEMORY_SCOPE_AGENT);
}
// CU-local L1 invalidate: subsequent plain loads are (at least) L2-fresh.
__device__ __forceinline__ void inv_l1() {
  asm volatile("buffer_inv\n\ts_waitcnt vmcnt(0)" ::: "memory");
  __builtin_amdgcn_sched_barrier(0);
}
// in-wave store drain (subset of inv_l1's proven asm): own stores acked at L2
__device__ __forceinline__ void drain_vm() {
  asm volatile("s_waitcnt vmcnt(0)" ::: "memory");
  __builtin_amdgcn_sched_barrier(0);
}
template <bool FAST>
__device__ __forceinline__ unsigned ldh(const unsigned* p) {
  if (FAST) return *p;     // plain load, L2-served (post-inv)
  return ld_lic(p);
}
template <bool FAST>
__device__ __forceinline__ void sth(unsigned* p, unsigned v) {
  if (FAST) *p = v;        // plain store: write-through L1 -> local L2
  else __hip_atomic_store(p, v, __ATOMIC_RELAXED, __HIP_MEMORY_SCOPE_AGENT);
}

// ---------------------------------------------------------------------------
// Per-layer persistent loop. LAYER=0: x(40->64 pad)+h1_prev, K=320.
// LAYER=1: h1_t + h2_prev, K=512; every layer1 wg emits y for 2 batches.
// Subflag (wave w of wg gg) value = steps completed by that wave.
// ---------------------------------------------------------------------------
template <int KSTEPS, int LAYER, bool FAST>
__device__ __forceinline__ void run_layer(
    int tid, int gg, int b0, int u0,
    const float* __restrict__ x, float* __restrict__ out, float blinv,
    unsigned short* __restrict__ h1bc, unsigned short* __restrict__ h2bc,
    int* __restrict__ c0s, int* __restrict__ c1s,
    unsigned short (*WL)[LDSK], unsigned short (*inA2)[LDSK],
    float* biasS, float* wlinS) {
  const int lane = tid & 63, wv = tid >> 6;
  const int quad = lane >> 4, l15 = lane & 15;
  const int Mt = wv & 1, Np = wv >> 1;   // wave -> (batch-tile, r-tile-pair)
  const int gb = b0 >> 5;
  const int irow = tid >> 3, icol = tid & 7;   // gather->LDS scatter coords

  // poll/flag pointers: lane l watches own-layer subflag l + other-layer l
  const int* ownS = (LAYER ? c1s : c0s) + lane * 4;
  const int* othS = (LAYER ? c0s : c1s) + lane * 4;
  int* mysub = (LAYER ? c1s : c0s) + (wv * 16 + gg) * 4;

  // Preload W fragments (constant across time), MFMA A-operand (R12-proven).
  short8 wfrag[2][KSTEPS];
#pragma unroll
  for (int ks = 0; ks < KSTEPS; ++ks) {
#pragma unroll
    for (int i = 0; i < 2; ++i)
      wfrag[i][ks] = *(const short8*)&WL[Np * 32 + i * 16 + l15][ks * 32 + quad * 8];
  }

  // gate biases for this lane's rows (R12-proven layout)
  float4v b4A = *(const float4v*)&biasS[Np * 32 + quad * 4];
  float4v b4B = *(const float4v*)&biasS[Np * 32 + 16 + quad * 4];

  // x prefetch registers (layer0, threads 0..127): holds x[t] during step t-1
  float xr[10];
  if (LAYER == 0 && tid < 128) {
    int b = tid >> 2, c = tid & 3;
    const float* xp0 = x + ((size_t)(b0 + b) * T_LEN + 0) * NX + c * 10;
#pragma unroll
    for (int j = 0; j < 10; ++j) xr[j] = xp0[j];
  }

  // cell state: lane owns (unit Np*8+quad, batch Mt*16+l15) -> cA; +4 -> cB
  float cA = 0.f, cB = 0.f;

#pragma unroll 1
  for (int t = 0; t < T_LEN; ++t) {
    // ---- wait for producers: ALL waves poll (sc1 loads, always fresh).
    //      thresholds identical to R12's wg-level conditions.
    {
      const int thrOwn = t;
      const int thrOth = LAYER ? (t + 1) : (t - RING + 1);
      while (ld_flag(ownS) < thrOwn) __builtin_amdgcn_s_sleep(1);
      while (ld_flag(othS) < thrOth) __builtin_amdgcn_s_sleep(1);
    }
    if (!FAST) __syncthreads();                     // slow: barrier #1
    if (FAST && (LAYER == 1 || t > 0)) inv_l1();    // per-wave L1 drop

    unsigned short (*inbuf)[LDSK] = inA2 + (t & 1) * MB;   // double buffer

    // ---- stage inputs into LDS (bf16); scalar dword gather (proven) ----
    if (LAYER == 0) {
      unsigned v[16];
      if (t > 0) {
        const unsigned* s1 = (const unsigned*)h1bc +
            ((size_t)((t - 1) & (RING - 1)) * RSTEP + (size_t)gb * 4096);
#pragma unroll
        for (int k = 0; k < 16; ++k) v[k] = ldh<FAST>(s1 + tid + k * 256);
      }
      if (tid < 128) {   // x[b,t,0:40] from prefetch regs (40..63 stay zero)
        int b = tid >> 2, c = tid & 3;
#pragma unroll
        for (int j = 0; j < 10; ++j) inbuf[b][c * 10 + j] = f2bf(xr[j]);
        if (t + 1 < T_LEN) {   // issue x[t+1] now: drained long before flag
          const float* xp = x + ((size_t)(b0 + b) * T_LEN + (size_t)(t + 1)) * NX + c * 10;
#pragma unroll
          for (int j = 0; j < 10; ++j) xr[j] = xp[j];
        }
      }
      if (t > 0) {
#pragma unroll
        for (int k = 0; k < 16; ++k)   // dword (gg=k, up=icol) of batch irow
          ((unsigned*)&inbuf[irow][0])[32 + k * 8 + icol] = v[k];   // +XP
      }
    } else {
      const unsigned* s1 = (const unsigned*)h1bc +
          ((size_t)(t & (RING - 1)) * RSTEP + (size_t)gb * 4096);
      unsigned va[16], vb[16];
#pragma unroll
      for (int k = 0; k < 16; ++k) va[k] = ldh<FAST>(s1 + tid + k * 256);
      if (t > 0) {
        const unsigned* s2 = (const unsigned*)h2bc +
            ((size_t)((t - 1) & (RING - 1)) * RSTEP + (size_t)gb * 4096);
#pragma unroll
        for (int k = 0; k < 16; ++k) vb[k] = ldh<FAST>(s2 + tid + k * 256);
      }
#pragma unroll
      for (int k = 0; k < 16; ++k) {
        unsigned* row = (unsigned*)&inbuf[irow][0];
        row[k * 8 + icol] = va[k];                    // h1 at ushort 0
        if (t > 0) row[128 + k * 8 + icol] = vb[k];   // h2 at ushort HP
      }
    }
    __syncthreads();   // the ONE barrier: staging -> MFMA

    // ---- gate GEMM, operand-swapped: D[r][b] (R12-proven) ----
    float4v acc0 = {0.f, 0.f, 0.f, 0.f};
    float4v acc1 = {0.f, 0.f, 0.f, 0.f};
#pragma unroll
    for (int ks = 0; ks < KSTEPS; ++ks) {
      short8 a = *(const short8*)&inbuf[Mt * 16 + l15][ks * 32 + quad * 8];
      acc0 = __builtin_amdgcn_mfma_f32_16x16x32_bf16(wfrag[0][ks], a, acc0, 0, 0, 0);
      acc1 = __builtin_amdgcn_mfma_f32_16x16x32_bf16(wfrag[1][ks], a, acc1, 0, 0, 0);
    }

    // ---- gates in-register (R12-proven lane layout) ----
    float hA, hB;
    {
      float i0 = sigm(acc0[0] + b4A[0]);
      float f0 = sigm(acc0[1] + b4A[1]);
      float g0 = tanh_f(acc0[2] + b4A[2]);
      float o0 = sigm(acc0[3] + b4A[3]);
      cA = f0 * cA + i0 * g0;
      hA = o0 * tanh_f(cA);
      float i1 = sigm(acc1[0] + b4B[0]);
      float f1 = sigm(acc1[1] + b4B[1]);
      float g1 = tanh_f(acc1[2] + b4B[2]);
      float o1 = sigm(acc1[3] + b4B[3]);
      cB = f1 * cB + i1 * g1;
      hB = o1 * tanh_f(cB);
    }
    // pack unit pairs (lane^16) and store to the ring (R12-proven mapping)
    {
      float hA2 = __shfl_xor(hA, 16);
      float hB2 = __shfl_xor(hB, 16);
      if ((quad & 1) == 0) {
        unsigned dwA = (unsigned)f2bf(hA) | ((unsigned)f2bf(hA2) << 16);
        unsigned dwB = (unsigned)f2bf(hB) | ((unsigned)f2bf(hB2) << 16);
        unsigned* dst = (unsigned*)(LAYER ? h2bc : h1bc);
        size_t base = (size_t)(t & (RING - 1)) * RSTEP + (size_t)gb * 4096 +
                      (size_t)gg * 256 + (size_t)(Mt * 16 + l15) * 8;
        sth<FAST>(dst + base + Np * 4 + (quad >> 1), dwA);
        sth<FAST>(dst + base + Np * 4 + 2 + (quad >> 1), dwB);
      }
    }

    // ---- signal: FAST = per-wave (drain own stores, lane0 subflag, no
    //      barrier); slow = barrier then per-wave sc1 subflag.
    if (FAST) {
      drain_vm();
      if (lane == 0) sth<true>((unsigned*)mysub, (unsigned)(t + 1));
    } else {
      __syncthreads();
      if (lane == 0) sth<false>((unsigned*)mysub, (unsigned)(t + 1));
    }

    // ---- head: y[b, t-1] — distributed (2 batches/wg), after signal ----
    if (LAYER == 1 && t > 0 && tid < 16) {
      int eb2 = 2 * gg + (tid >> 3), uc = tid & 7;
      float sum = 0.f;
#pragma unroll
      for (int j = 0; j < 4; ++j) {
        short8 hvv = *(const short8*)&inbuf[eb2][HP + uc * 32 + j * 8];
#pragma unroll
        for (int e = 0; e < 8; ++e)
          sum += bf2f((unsigned short)hvv[e]) * wlinS[uc * 32 + j * 8 + e];
      }
      sum += __shfl_xor(sum, 1);
      sum += __shfl_xor(sum, 2);
      sum += __shfl_xor(sum, 4);
      if ((tid & 7) == 0)
        out[(size_t)(b0 + eb2) * T_LEN + (t - 1)] = sigm(sum + blinv);
    }
  }

  // ---- epilogue: y[:, 511] — distributed: every layer1 wg, 2 batches ----
  if (LAYER == 1) {
    if (wv == 0) {
      const int* sl = c1s + lane * 4;
      while (ld_flag(sl) < T_LEN) __builtin_amdgcn_s_sleep(1);
    }
    __syncthreads();
    if (FAST) inv_l1();
    if (tid < 16) {
      int eb2 = 2 * gg + (tid >> 3), uc = tid & 7;
      const unsigned* base = (const unsigned*)h2bc +
          ((size_t)(511 & (RING - 1)) * RSTEP + (size_t)gb * 4096);
      float sum = 0.f;
#pragma unroll
      for (int g = 0; g < 2; ++g) {
        const unsigned* src = base + (size_t)(2 * uc + g) * 256 + eb2 * 8;
#pragma unroll
        for (int j = 0; j < 8; ++j) {
          unsigned dw = ldh<FAST>(src + j);
          sum += bf2f((unsigned short)(dw & 0xFFFFu)) * wlinS[uc * 32 + g * 16 + 2 * j];
          sum += bf2f((unsigned short)(dw >> 16)) * wlinS[uc * 32 + g * 16 + 2 * j + 1];
        }
      }
      sum += __shfl_xor(sum, 1);
      sum += __shfl_xor(sum, 2);
      sum += __shfl_xor(sum, 4);
      if ((tid & 7) == 0)
        out[(size_t)(b0 + eb2) * T_LEN + 511] = sigm(sum + blinv);
    }
  }
}

// ---------------------------------------------------------------------------
extern "C" __global__ void __launch_bounds__(256, 1) lstm_persist(
    const float* __restrict__ x,
    const float* __restrict__ Wih0, const float* __restrict__ Whh0,
    const float* __restrict__ bih0, const float* __restrict__ bhh0,
    const float* __restrict__ Wih1, const float* __restrict__ Whh1,
    const float* __restrict__ bih1, const float* __restrict__ bhh1,
    const float* __restrict__ Wlin, const float* __restrict__ blin,
    float* __restrict__ out,
    unsigned short* __restrict__ h1bc, unsigned short* __restrict__ h2bc,
    int* __restrict__ cnt) {
  __shared__ unsigned short WL[NR][LDSK];      // 66560 B  bf16 [r][k]
  __shared__ unsigned short inA[2 * MB][LDSK]; // 66560 B  double-buffered acts
  __shared__ float biasS[NR];
  __shared__ float wlinS[HP];

  const int tid = threadIdx.x;
  const int wg = blockIdx.x;

  // ---- XCD discovery + dynamic clustering (one-time, off steady state) ----
  const unsigned xcc = ((unsigned)__builtin_amdgcn_s_getreg(GETREG_XCC)) & 15u;
  if (tid == 0) {
    __hip_atomic_store(cnt + XCD_AT(wg), (int)xcc, __ATOMIC_RELAXED,
                       __HIP_MEMORY_SCOPE_AGENT);
    __hip_atomic_fetch_add(cnt + BAR_IDX, 1, __ATOMIC_ACQ_REL,
                           __HIP_MEMORY_SCOPE_AGENT);
    while (__hip_atomic_load(cnt + BAR_IDX, __ATOMIC_ACQUIRE,
                             __HIP_MEMORY_SCOPE_AGENT) < 256)
      __builtin_amdgcn_s_sleep(8);
  }
  __syncthreads();
  int* sx = (int*)&inA[0][0];   // inA as 256-int scratch (pre-zeroing)
  sx[tid] = __hip_atomic_load(cnt + XCD_AT(tid), __ATOMIC_RELAXED,
                              __HIP_MEMORY_SCOPE_AGENT);
  __syncthreads();
  const int myv = sx[wg];
  int rank = 0;
  unsigned long long hist = 0;
  bool ok = true;
  for (int j = 0; j < 256; ++j) {
    int v = sx[j];
    if ((unsigned)v > 7u) { ok = false; v = 0; }
    hist += 1ull << (v * 8);
    if (v == myv && j < wg) rank++;
  }
  ok = ok && (hist == 0x2020202020202020ull);   // exactly 32 wgs per XCD
  __syncthreads();   // sx (inA) free for zero-fill below

  // Roles: fast -> cluster = this XCD; slow -> static mapping + sc1 ops.
  int layer, gb, gg;
  if (ok) { gb = myv;       layer = rank >> 4;    gg = rank & 15; }
  else    { layer = wg >> 7; gb = (wg >> 4) & 7;  gg = wg & 15;   }
  const int b0 = gb * MB, u0 = gg * NU;

  // ---- one-time LDS fills ----
  {
    const float* Wih = layer ? Wih1 : Wih0;
    const float* Whh = layer ? Whh1 : Whh0;
    const float* bi = layer ? bih1 : bih0;
    const float* bh = layer ? bhh1 : bhh0;
    const int K = layer ? K1 : K0;
    const int xw = layer ? NH : NX;     // real width of input-part
    const int xofs = layer ? HP : XP;   // where h-part starts
    int r = tid >> 2, c = tid & 3;
    int lu = r >> 2, g = r & 3, ug = u0 + lu;
    int row = g * NH + ug;
    int kq = K >> 2;
    for (int k = c * kq; k < (c + 1) * kq; ++k) {
      float v = 0.f;
      if (ug < NH) {
        if (k < xw) v = Wih[(size_t)row * xw + k];
        else if (k >= xofs && k < xofs + NH) v = Whh[(size_t)row * NH + (k - xofs)];
      }
      WL[r][k] = f2bf(v);
    }
    if (tid < NR) {
      int lu2 = tid >> 2, g2 = tid & 3, ug2 = u0 + lu2;
      biasS[tid] = (ug2 < NH) ? (bi[g2 * NH + ug2] + bh[g2 * NH + ug2]) : 0.f;
    }
    if (tid < HP) wlinS[tid] = (tid < NH) ? Wlin[tid] : 0.f;
    for (int i = tid; i < 2 * MB * LDSK; i += 256) ((unsigned short*)inA)[i] = 0;
  }
  __syncthreads();

  float blinv = blin[0];
  int* c0s = cnt + gb * GSTRIDE;            // layer0 subflags, batch-group gb
  int* c1s = cnt + (8 + gb) * GSTRIDE;      // layer1 subflags

  if (ok) {
    if (layer == 0)
      run_layer<K0 / 32, 0, true>(tid, gg, b0, u0, x, out, blinv, h1bc, h2bc,
                                  c0s, c1s, WL, inA, biasS, wlinS);
    else
      run_layer<K1 / 32, 1, true>(tid, gg, b0, u0, x, out, blinv, h1bc, h2bc,
                                  c0s, c1s, WL, inA, biasS, wlinS);
  } else {
    if (layer == 0)
      run_layer<K0 / 32, 0, false>(tid, gg, b0, u0, x, out, blinv, h1bc, h2bc,
                                   c0s, c1s, WL, inA, biasS, wlinS);
    else
      run_layer<K1 / 32, 1, false>(tid, gg, b0, u0, x, out, blinv, h1bc, h2bc,
                                   c0s, c1s, WL, inA, biasS, wlinS);
  }
}

extern "C" __global__ void prep_zero(int* cnt) {
  int i = blockIdx.x * 256 + threadIdx.x;
  if (i < NFLAG)   // subflag slots incl. embedded barrier/xcd-id padding ints
    __hip_atomic_store(cnt + i, 0, __ATOMIC_RELAXED, __HIP_MEMORY_SCOPE_AGENT);
}

// ---------------------------------------------------------------------------
extern "C" void kernel_launch(void* const* d_in, const int* in_sizes, int n_in,
                              void* d_out, int out_size, void* d_ws, size_t ws_size,
                              hipStream_t stream) {
  const float* x    = (const float*)d_in[0];
  const float* Wih0 = (const float*)d_in[1];
  const float* Whh0 = (const float*)d_in[2];
  const float* bih0 = (const float*)d_in[3];
  const float* bhh0 = (const float*)d_in[4];
  const float* Wih1 = (const float*)d_in[5];
  const float* Whh1 = (const float*)d_in[6];
  const float* bih1 = (const float*)d_in[7];
  const float* bhh1 = (const float*)d_in[8];
  const float* Wlin = (const float*)d_in[9];
  const float* blin = (const float*)d_in[10];
  float* out = (float*)d_out;

  // workspace carve (same footprint as R3..R12): h rings 2x2MB | flags 16KB
  unsigned short* h1bc = (unsigned short*)d_ws;
  unsigned short* h2bc = h1bc + (size_t)RING * B_TOT * HP;
  int* cnt = (int*)((char*)d_ws + 2u * (size_t)RING * B_TOT * HP * sizeof(unsigned short));

  hipLaunchKernelGGL(prep_zero, dim3(16), dim3(256), 0, stream, cnt);

  void* args[] = {&x, &Wih0, &Whh0, &bih0, &bhh0, &Wih1, &Whh1, &bih1, &bhh1,
                  &Wlin, &blin, &out, &h1bc, &h2bc, &cnt};
  hipLaunchCooperativeKernel((void*)lstm_persist, dim3(256), dim3(256), args, 0u, stream);
}